// Round 10
// baseline (13079.323 us; speedup 1.0000x reference)
//
#include <hip/hip_runtime.h>
#include <hip/hip_bf16.h>

#define B_ 256
#define T_ 256
#define F_ 512
#define H_ 1024
#define A_ 1000
#define EPS_ 1e-7f

typedef __hip_bfloat16 bf16;

// ---------------------------------------------------------------------------
// State of knowledge (round 19 == round 18 resubmit; r18 bench died on
// GPUAcquisitionTimeout — the persistent rnn_scan kernel has never run):
//  - CORRECTNESS LOCKED (harness-verified r9 @31109, r10 @14771, r12 @5401,
//    r15 @7078, r17 @5611us, all absmax 0.0): d_out FLOAT32 [action(256),
//    loss(1)]; RNG = V4 partitionable xor-fold threefry (o0^o1),
//    key(42)->(0,42); gumbel-argmax first-index tie-break; dtype
//    runtime-detect from Wx. detect/sample/finalize/gemm/xw_gemm/threefry
//    byte-identical to verified. DO NOT TOUCH.
//  - Scan-step ladder (us/step): r9 ~120 -> r10 ~40 -> r12 v2 ~14.5 ->
//    r15 v3 ~21 REGRESS -> r17 v4 ~15.3 NEUTRAL.
//  - KEY OBSERVATION r17: v2 and v4 (totally different internals) hit the
//    SAME ~15us/step floor; v4's in-kernel model is ~5us. The floor is
//    PER-LAUNCH overhead of 256 serial dispatches (ramp + drain-to-max +
//    graph node latency) + v4's per-step 64KB panel reload.
//  - r18/r19: persistent chunk-scan. ONE launch = 32 steps; in-kernel grid
//    barrier (generation-counter device-scope atomics; __threadfence()
//    writeback + ACQUIRE spin loads = sanctioned cross-XCD pattern, G16).
//    Co-residency GUARANTEED: 128KB LDS -> exactly 1 block/CU, 256 blocks
//    = 256 CUs. Panel loaded once per chunk. Step math/sum order byte-
//    identical to v4 (verified). Launches 264 -> 21.
//  - Predict: step ~8us (5 compute + 3 barrier); chunk dispatch 260-300us;
//    total 5611 -> ~3.6-4.0ms. Decision: (a) ok -> attack xw_gemm next /
//    fold xw into persistent kernel; (b) chunk >400us -> barrier too
//    costly, hybrid sub-chunks; (c) pytest hang -> co-residency/fence bug,
//    revert to r17; (d) absmax!=0 -> fence issue, revert; (e) infra ->
//    resubmit.
// ---------------------------------------------------------------------------
__global__ __launch_bounds__(256) void detect_kernel(
    const unsigned* __restrict__ wx_words, int* __restrict__ flag)
{
    __shared__ int cnt[256];
    const int tid = threadIdx.x;
    int c = 0;
    for (int k = tid; k < 65536; k += 256) {
        unsigned lo = wx_words[k] & 0xFFFFu;
        unsigned e = (lo >> 7) & 0xFFu;
        if (e >= 105u && e <= 126u) c++;   // |v| in [2^-22, 0.5]: bf16 weight-like
    }
    cnt[tid] = c;
    __syncthreads();
    for (int s = 128; s > 0; s >>= 1) {
        if (tid < s) cnt[tid] += cnt[tid + s];
        __syncthreads();
    }
    if (tid == 0) flag[0] = (cnt[0] > 32768) ? 1 : 0;   // 1 => bf16-packed
}

__device__ __forceinline__ float load_maybe(const void* p, long i, int isbf16)
{
    return isbf16 ? __bfloat162float(((const bf16*)p)[i])
                  : ((const float*)p)[i];
}

// ---------------------------------------------------------------------------
// OLD fused GEMM (verified): kept for fallback path and layers 2/3.
// ---------------------------------------------------------------------------
__global__ __launch_bounds__(256) void gemm_kernel(
    const void* __restrict__ A1, int a1_maybe, long a1_off, int lda1, int K1,
    const float* __restrict__ A2, int lda2, int K2,
    const void* __restrict__ Wa, const void* __restrict__ Wb,
    const void* __restrict__ bias,
    const int* __restrict__ flagp,
    float* __restrict__ C, int M, int N, int do_relu)
{
    const int flagv = flagp[0];          // uniform; L2-hit
    const int a1_bf = a1_maybe ? flagv : 0;

    __shared__ float As[32][33];
    __shared__ float Bs[32][33];

    const int tid = threadIdx.x;
    const int tx = tid & 15;
    const int ty = tid >> 4;
    const int n0 = blockIdx.x * 32;
    const int m0 = blockIdx.y * 32;

    float acc00 = 0.f, acc01 = 0.f, acc10 = 0.f, acc11 = 0.f;

    for (int part = 0; part < 2; ++part) {
        const void* Wp = part ? Wb : Wa;
        const int    K = part ? K2 : K1;
        if (part == 1 && (A2 == nullptr || K2 <= 0)) continue;

        for (int k0 = 0; k0 < K; k0 += 32) {
            #pragma unroll
            for (int i = 0; i < 4; ++i) {
                int idx = tid + i * 256;
                int r = idx >> 5, c = idx & 31;
                float av;
                if (part == 0) {
                    long off = a1_off + (long)(m0 + r) * lda1 + (k0 + c);
                    av = load_maybe(A1, off, a1_bf);
                } else {
                    av = A2[(long)(m0 + r) * lda2 + (k0 + c)];
                }
                As[r][c] = av;
                int n = n0 + c;
                Bs[r][c] = (n < N) ? load_maybe(Wp, (long)(k0 + r) * N + n, flagv)
                                   : 0.0f;
            }
            __syncthreads();
            #pragma unroll
            for (int k = 0; k < 32; ++k) {
                float a0 = As[ty * 2][k];
                float a1 = As[ty * 2 + 1][k];
                float b0 = Bs[k][tx * 2];
                float b1 = Bs[k][tx * 2 + 1];
                acc00 = fmaf(a0, b0, acc00); acc01 = fmaf(a0, b1, acc01);
                acc10 = fmaf(a1, b0, acc10); acc11 = fmaf(a1, b1, acc11);
            }
            __syncthreads();
        }
    }

    const int m = m0 + ty * 2;
    const int n = n0 + tx * 2;
    float bs0 = (n     < N) ? load_maybe(bias, n,     flagv) : 0.0f;
    float bs1 = (n + 1 < N) ? load_maybe(bias, n + 1, flagv) : 0.0f;
    float v00 = acc00 + bs0, v01 = acc01 + bs1;
    float v10 = acc10 + bs0, v11 = acc11 + bs1;
    if (do_relu) {
        v00 = fmaxf(v00, 0.f); v01 = fmaxf(v01, 0.f);
        v10 = fmaxf(v10, 0.f); v11 = fmaxf(v11, 0.f);
    }
    if (n     < N) C[(long)m * N + n]           = v00;
    if (n + 1 < N) C[(long)m * N + n + 1]       = v01;
    if (n     < N) C[(long)(m + 1) * N + n]     = v10;
    if (n + 1 < N) C[(long)(m + 1) * N + n + 1] = v11;
}

// ---------------------------------------------------------------------------
// XW chunk GEMM (verified r10). C[8192][1024] = inputs_chunk @ Wx + b_rnn.
// Chunk rows r = b*32 + tl  <->  input row b*256 + (t0 + tl).
// 128x128 tile, BK=16, 8x8 micro, 256 threads. Grid (8, 64).
// ---------------------------------------------------------------------------
__global__ __launch_bounds__(256, 2) void xw_gemm_kernel(
    const void* __restrict__ X,      // inputs, dual dtype
    const void* __restrict__ Wx,     // [512][1024], dual dtype
    const void* __restrict__ brnn,   // [1024], dual dtype
    const int* __restrict__ flagp,
    float* __restrict__ C,           // [8192][1024] chunk buffer
    int t0)
{
    const int flagv = flagp[0];
    __shared__ float As[16][132];    // k-major: As[k][m]
    __shared__ float Bs[16][132];    // Bs[k][n]

    const int tid = threadIdx.x;
    const int tx = tid & 15;
    const int ty = tid >> 4;
    const int n0 = blockIdx.x * 128;
    const int m0 = blockIdx.y * 128;

    float acc[8][8] = {{0.f}};

    for (int k0 = 0; k0 < F_; k0 += 16) {
        #pragma unroll
        for (int i = 0; i < 8; ++i) {
            int idx = tid + i * 256;            // 0..2047
            // A: 128 rows x 16 k, consecutive tid -> consecutive k
            int ka = idx & 15, r = idx >> 4;
            int rg = m0 + r;
            long irow = (long)(rg >> 5) * 256 + t0 + (rg & 31);
            As[ka][r] = load_maybe(X, irow * F_ + k0 + ka, flagv);
            // B: 16 k x 128 n, consecutive tid -> consecutive n
            int nb = idx & 127, kb = idx >> 7;
            Bs[kb][nb] = load_maybe(Wx, (long)(k0 + kb) * H_ + n0 + nb, flagv);
        }
        __syncthreads();
        #pragma unroll
        for (int k = 0; k < 16; ++k) {
            float4 a0 = *(const float4*)&As[k][ty * 4];
            float4 a1 = *(const float4*)&As[k][ty * 4 + 64];
            float4 b0 = *(const float4*)&Bs[k][tx * 4];
            float4 b1 = *(const float4*)&Bs[k][tx * 4 + 64];
            float av[8] = {a0.x, a0.y, a0.z, a0.w, a1.x, a1.y, a1.z, a1.w};
            float bv[8] = {b0.x, b0.y, b0.z, b0.w, b1.x, b1.y, b1.z, b1.w};
            #pragma unroll
            for (int i = 0; i < 8; ++i)
                #pragma unroll
                for (int j = 0; j < 8; ++j)
                    acc[i][j] = fmaf(av[i], bv[j], acc[i][j]);
        }
        __syncthreads();
    }

    float bb[8];
    #pragma unroll
    for (int j = 0; j < 8; ++j) {
        int n = n0 + tx * 4 + (j & 3) + (j >> 2) * 64;
        bb[j] = load_maybe(brnn, n, flagv);
    }
    #pragma unroll
    for (int i = 0; i < 8; ++i) {
        int m = m0 + ty * 4 + (i & 3) + (i >> 2) * 64;
        float4 v0 = {acc[i][0] + bb[0], acc[i][1] + bb[1],
                     acc[i][2] + bb[2], acc[i][3] + bb[3]};
        float4 v1 = {acc[i][4] + bb[4], acc[i][5] + bb[5],
                     acc[i][6] + bb[6], acc[i][7] + bb[7]};
        *(float4*)&C[(long)m * H_ + n0 + tx * 4]      = v0;
        *(float4*)&C[(long)m * H_ + n0 + tx * 4 + 64] = v1;
    }
}

// ---------------------------------------------------------------------------
// Wh -> fp32 copy (handles bf16-packed mode once, outside the scan).
// ---------------------------------------------------------------------------
__global__ __launch_bounds__(256) void convert_wh_kernel(
    const void* __restrict__ Wh, const int* __restrict__ flagp,
    float* __restrict__ whf)
{
    const int flagv = flagp[0];
    long i = (long)blockIdx.x * 256 + threadIdx.x;
    whf[i] = load_maybe(Wh, i, flagv);
}

// ---------------------------------------------------------------------------
// r18/r19: device-scope grid barrier (monotonic generation counter).
// Co-residency REQUIRED: caller guarantees 1 block/CU (128KB LDS) and
// grid size == 256 <= #CUs. Cross-XCD visibility: __threadfence() before
// arrival (L2 writeback on gfx9 multi-L2), ACQUIRE atomic spin on release.
// ---------------------------------------------------------------------------
__device__ __forceinline__ void grid_sync(int* cnt, int* gen, int nblk)
{
    __syncthreads();
    if (threadIdx.x == 0) {
        __threadfence();   // release prior stores device-wide
        int g = __hip_atomic_load(gen, __ATOMIC_RELAXED,
                                  __HIP_MEMORY_SCOPE_AGENT);
        int a = __hip_atomic_fetch_add(cnt, 1, __ATOMIC_ACQ_REL,
                                       __HIP_MEMORY_SCOPE_AGENT);
        if (a == nblk - 1) {
            __hip_atomic_store(cnt, 0, __ATOMIC_RELAXED,
                               __HIP_MEMORY_SCOPE_AGENT);
            __hip_atomic_store(gen, g + 1, __ATOMIC_RELEASE,
                               __HIP_MEMORY_SCOPE_AGENT);
        } else {
            while (__hip_atomic_load(gen, __ATOMIC_ACQUIRE,
                                     __HIP_MEMORY_SCOPE_AGENT) <= g) {
                __builtin_amdgcn_s_sleep(8);
            }
        }
        __threadfence();   // acquire side: invalidate stale caches
    }
    __syncthreads();
}

// ---------------------------------------------------------------------------
// r18/r19: persistent chunk scan — 32 steps in ONE launch.
// Per-step math/geometry BYTE-IDENTICAL to verified v4 (r17, absmax 0.0):
//   block (bx,by) owns 16n x 64m; wave q = k-segment (64k); per k:
//   1 coalesced global h + 4 ds_read_b128 panel broadcasts + 16 FMA;
//   part[16][16][64] combine ascending q; + xw; relu; coalesced store.
// Differences vs v4: panel loaded ONCE per chunk; ping-pong + grid_sync
// between steps instead of kernel relaunch. 32 steps even -> h returns to
// hT0 at chunk end.
// ---------------------------------------------------------------------------
__global__ __launch_bounds__(1024) void rnn_scan_kernel(
    float* __restrict__ hT0,          // [1024][256] in/out (chunk start+end)
    float* __restrict__ hT1,          // [1024][256] scratch
    const float* __restrict__ Wh,     // [1024][1024] fp32
    const float* __restrict__ xwbuf,  // [8192][1024] chunk XW
    int* __restrict__ cnt, int* __restrict__ gen)
{
    __shared__ float whp[1024][16];      // 64 KB Wh panel
    __shared__ float part[16][16][64];   // 64 KB partials [q][n][m]

    const int tid  = threadIdx.x;
    const int lane = tid & 63;
    const int q    = __builtin_amdgcn_readfirstlane(tid >> 6);  // k-segment
    const int n0   = blockIdx.x * 16;
    const int m0   = blockIdx.y * 64;

    // --- panel load ONCE per chunk: thread t -> Wh row t, cols n0..n0+15 ---
    {
        const float4* src = (const float4*)(Wh + (long)tid * H_ + n0);
        float4 p0 = src[0], p1 = src[1], p2 = src[2], p3 = src[3];
        *(float4*)&whp[tid][0]  = p0;
        *(float4*)&whp[tid][4]  = p1;
        *(float4*)&whp[tid][8]  = p2;
        *(float4*)&whp[tid][12] = p3;
    }
    __syncthreads();

    const int mi = tid & 63;          // combine-phase indices
    const int ni = tid >> 6;

    float* hp = hT0;
    float* hn = hT1;

    for (int tl = 0; tl < 32; ++tl) {
        // --- main: 64 k per wave, 16 FMA per k (identical to v4) ---
        const float* __restrict__ hq = hp + (((long)q << 6) << 8) + m0 + lane;
        float acc[16];
        #pragma unroll
        for (int i = 0; i < 16; ++i) acc[i] = 0.f;

        #pragma unroll 4
        for (int k = 0; k < 64; ++k) {
            float hv = hq[k << 8];             // hp[(q*64+k)*256 + m0+lane]
            const int kk = (q << 6) + k;
            float4 w0 = *(const float4*)&whp[kk][0];
            float4 w1 = *(const float4*)&whp[kk][4];
            float4 w2 = *(const float4*)&whp[kk][8];
            float4 w3 = *(const float4*)&whp[kk][12];
            acc[0]  = fmaf(hv, w0.x, acc[0]);
            acc[1]  = fmaf(hv, w0.y, acc[1]);
            acc[2]  = fmaf(hv, w0.z, acc[2]);
            acc[3]  = fmaf(hv, w0.w, acc[3]);
            acc[4]  = fmaf(hv, w1.x, acc[4]);
            acc[5]  = fmaf(hv, w1.y, acc[5]);
            acc[6]  = fmaf(hv, w1.z, acc[6]);
            acc[7]  = fmaf(hv, w1.w, acc[7]);
            acc[8]  = fmaf(hv, w2.x, acc[8]);
            acc[9]  = fmaf(hv, w2.y, acc[9]);
            acc[10] = fmaf(hv, w2.z, acc[10]);
            acc[11] = fmaf(hv, w2.w, acc[11]);
            acc[12] = fmaf(hv, w3.x, acc[12]);
            acc[13] = fmaf(hv, w3.y, acc[13]);
            acc[14] = fmaf(hv, w3.z, acc[14]);
            acc[15] = fmaf(hv, w3.w, acc[15]);
        }

        #pragma unroll
        for (int i = 0; i < 16; ++i) part[q][i][lane] = acc[i];
        __syncthreads();

        // --- combine ascending q; + xw; relu; store (identical to v4) ---
        float s = part[0][ni][mi];
        #pragma unroll
        for (int qq = 1; qq < 16; ++qq) s += part[qq][ni][mi];

        const int gm = m0 + mi;
        const int gn = n0 + ni;
        const float xv = xwbuf[(long)tl * 1024 + (long)gm * (32 * 1024) + gn];
        hn[(long)gn * 256 + gm] = fmaxf(s + xv, 0.f);

        // --- cross-block visibility + part-array reuse protection ---
        grid_sync(cnt, gen, 256);

        float* t = hp; hp = hn; hn = t;
    }
}

// ---------------------------------------------------------------------------
// transpose hT[1024][256] -> h_last[256][1024] for layer 2.
// ---------------------------------------------------------------------------
__global__ __launch_bounds__(256) void transpose_kernel(
    const float* __restrict__ in,   // [1024][256]
    float* __restrict__ out)        // [256][1024]
{
    __shared__ float t[32][33];
    const int tid = threadIdx.x;
    const int c  = tid & 31;
    const int r8 = tid >> 5;
    const int x0 = blockIdx.x * 32;   // over 1024
    const int y0 = blockIdx.y * 32;   // over 256
    #pragma unroll
    for (int i = 0; i < 4; ++i) {
        int r = r8 + i * 8;
        t[r][c] = in[(long)(x0 + r) * 256 + y0 + c];
    }
    __syncthreads();
    #pragma unroll
    for (int i = 0; i < 4; ++i) {
        int r = r8 + i * 8;
        out[(long)(y0 + r) * 1024 + x0 + c] = t[c][r];
    }
}

// ---------------------------------------------------------------------------
// Threefry2x32, 20 rounds — matches JAX exactly. key(42) => (k0,k1)=(0,42).
// ---------------------------------------------------------------------------
__device__ __forceinline__ unsigned rotl32(unsigned v, int r) {
    return (v << r) | (v >> (32 - r));
}

__device__ __forceinline__ void threefry2x32(unsigned k0, unsigned k1,
                                             unsigned x0, unsigned x1,
                                             unsigned& o0, unsigned& o1)
{
    unsigned ks2 = k0 ^ k1 ^ 0x1BD11BDAu;
    x0 += k0; x1 += k1;
#define R4(ra, rb, rc, rd)                              \
    x0 += x1; x1 = rotl32(x1, ra); x1 ^= x0;            \
    x0 += x1; x1 = rotl32(x1, rb); x1 ^= x0;            \
    x0 += x1; x1 = rotl32(x1, rc); x1 ^= x0;            \
    x0 += x1; x1 = rotl32(x1, rd); x1 ^= x0;
    R4(13, 15, 26, 6);  x0 += k1;  x1 += ks2 + 1u;
    R4(17, 29, 16, 24); x0 += ks2; x1 += k0  + 2u;
    R4(13, 15, 26, 6);  x0 += k0;  x1 += k1  + 3u;
    R4(17, 29, 16, 24); x0 += k1;  x1 += ks2 + 4u;
    R4(13, 15, 26, 6);  x0 += ks2; x1 += k0  + 5u;
#undef R4
    o0 = x0; o1 = x1;
}

// Gumbel at flat index j of the (256,1000) draw, key(42).
// V4 partitionable xor-fold (VERIFIED): counts (hi=0, lo=j), bits = o0^o1.
__device__ __forceinline__ float gumbel_at(unsigned j)
{
    unsigned o0, o1;
    threefry2x32(0u, 42u, 0u, j, o0, o1);
    unsigned bits = o0 ^ o1;                       // V4: xor-fold
    unsigned ub = (bits >> 9) | 0x3F800000u;       // [1,2)
    float u = __uint_as_float(ub) - 1.0f;          // [0,1)
    const float TINY = 1.1754943508222875e-38f;    // finfo(f32).tiny
    u = fmaxf(TINY, u * (1.0f - TINY) + TINY);     // JAX uniform(minval=tiny)
    return -logf(-logf(u));
}

// ---------------------------------------------------------------------------
// Softmax + gumbel-argmax sampling + loss. One block per batch row.
// OUTPUT IS FLOAT32. besti canary = 500.
// ---------------------------------------------------------------------------
__global__ __launch_bounds__(256) void sample_kernel(
    const float* __restrict__ logits,      // [B_, A_]
    float* __restrict__ out,               // out[b] = action as float32
    float* __restrict__ loss_acc)          // pre-zeroed scalar
{
    const int b = blockIdx.x;
    const int tid = threadIdx.x;
    const float* row = logits + (long)b * A_;

    __shared__ float sv[256];
    __shared__ int   si[256];

    // 1. row max
    float lv[4];
    float lmax = -INFINITY;
    #pragma unroll
    for (int i = 0; i < 4; ++i) {
        int a = tid + i * 256;
        lv[i] = (a < A_) ? row[a] : -INFINITY;
        lmax = fmaxf(lmax, lv[i]);
    }
    sv[tid] = lmax;
    __syncthreads();
    for (int s = 128; s > 0; s >>= 1) {
        if (tid < s) sv[tid] = fmaxf(sv[tid], sv[tid + s]);
        __syncthreads();
    }
    lmax = sv[0];
    __syncthreads();

    // 2. exp + sum
    float e[4];
    float lsum = 0.f;
    #pragma unroll
    for (int i = 0; i < 4; ++i) {
        int a = tid + i * 256;
        e[i] = (a < A_) ? expf(lv[i] - lmax) : 0.0f;
        lsum += e[i];
    }
    sv[tid] = lsum;
    __syncthreads();
    for (int s = 128; s > 0; s >>= 1) {
        if (tid < s) sv[tid] += sv[tid + s];
        __syncthreads();
    }
    const float inv = 1.0f / sv[0];
    __syncthreads();

    // 3. score = prob + gumbel; argmax, first-index tie-break (np.argmax)
    float bestv = -INFINITY;
    int   besti = 500;                     // NaN canary
    #pragma unroll
    for (int i = 0; i < 4; ++i) {
        int a = tid + i * 256;
        if (a < A_) {
            float score = e[i] * inv + gumbel_at((unsigned)(b * A_ + a));
            if (score > bestv) { bestv = score; besti = a; }
        }
    }
    sv[tid] = bestv; si[tid] = besti;
    __syncthreads();
    for (int s = 128; s > 0; s >>= 1) {
        if (tid < s) {
            float v2 = sv[tid + s]; int i2 = si[tid + s];
            if (v2 > sv[tid] || (v2 == sv[tid] && i2 < si[tid])) {
                sv[tid] = v2; si[tid] = i2;
            }
        }
        __syncthreads();
    }

    if (tid == 0) {
        int act = si[0];
        out[b] = (float)act;                       // float32 action
        float p = expf(row[act] - lmax) * inv;
        p = fminf(fmaxf(p, EPS_), 1.0f - EPS_);
        atomicAdd(loss_acc, -logf(p) * (1.0f / (float)B_));
    }
}

__global__ void finalize_kernel(const float* __restrict__ loss_acc,
                                float* __restrict__ out)
{
    out[B_] = *loss_acc;                           // float32 loss
}

// ---------------------------------------------------------------------------
extern "C" void kernel_launch(void* const* d_in, const int* in_sizes, int n_in,
                              void* d_out, int out_size, void* d_ws, size_t ws_size,
                              hipStream_t stream)
{
    (void)out_size;

    // Size-based pointer mapping (removes any ordering assumption).
    const void *inputs = nullptr, *Wx = nullptr, *Wh = nullptr, *b_rnn = nullptr,
               *W1 = nullptr, *b1 = nullptr, *W2 = nullptr, *b2 = nullptr;
    for (int i = 0; i < n_in; ++i) {
        int s = in_sizes[i];
        if      (s == 33554432) inputs = d_in[i];
        else if (s == 524288)   Wx = d_in[i];
        else if (s == 1048576)  { if (!Wh) Wh = d_in[i]; else W1 = d_in[i]; }
        else if (s == 1024)     { if (!b_rnn) b_rnn = d_in[i]; else b1 = d_in[i]; }
        else if (s == 1024000)  W2 = d_in[i];
        else if (s == 1000)     b2 = d_in[i];
    }
    if (!inputs) inputs = d_in[0];
    if (!Wx) Wx = d_in[1];  if (!Wh) Wh = d_in[2];  if (!b_rnn) b_rnn = d_in[3];
    if (!W1) W1 = d_in[4];  if (!b1) b1 = d_in[5];  if (!W2) W2 = d_in[6];
    if (!b2) b2 = d_in[7];

    float* out = (float*)d_out;            // FLOAT32 output buffer
    float* ws = (float*)d_ws;

    dim3 blk(256);
    dim3 grdH((H_ + 31) / 32, B_ / 32);   // 32 x 8
    dim3 grdA((A_ + 31) / 32, B_ / 32);

    // Workspace demand for the fast path (~43 MB in floats):
    const size_t XW_FLOATS = (size_t)8192 * 1024;     // 8,388,608 (32-t chunk)
    const size_t need_floats = XW_FLOATS + 2 * 262144 + 1048576
                             + 262144 + 262144 + 256000 + 8;
    if (ws_size >= need_floats * sizeof(float)) {
        // ---------------- FAST PATH (round 19) ----------------
        float* xwbuf    = ws;                          // [8192][1024]
        float* hT0      = xwbuf + XW_FLOATS;           // [1024][256]
        float* hT1      = hT0 + 262144;                // [1024][256]
        float* whf      = hT1 + 262144;                // [1024][1024]
        float* hlast    = whf + 1048576;               // [256][1024]
        float* hid      = hlast + 262144;              // [256][1024]
        float* logits   = hid + 262144;                // [256][1000]
        float* loss_acc = logits + 256000;             // [1]
        int*   flag     = (int*)(loss_acc + 1);        // [1]
        int*   barrier  = flag + 1;                    // [2] cnt, gen

        hipMemsetAsync(hT0, 0, 262144 * sizeof(float), stream);
        hipMemsetAsync(loss_acc, 0, sizeof(float), stream);
        hipMemsetAsync(barrier, 0, 2 * sizeof(int), stream);

        // 0. dtype detect, Wh -> fp32
        detect_kernel<<<1, blk, 0, stream>>>((const unsigned*)Wx, flag);
        convert_wh_kernel<<<4096, blk, 0, stream>>>(Wh, flag, whf);

        // 1. scan: per 32-t chunk, precompute XW then ONE persistent launch
        for (int c = 0; c < 8; ++c) {
            xw_gemm_kernel<<<dim3(8, 64), blk, 0, stream>>>(
                inputs, Wx, b_rnn, flag, xwbuf, c * 32);
            rnn_scan_kernel<<<dim3(64, 4), dim3(1024), 0, stream>>>(
                hT0, hT1, whf, xwbuf, barrier, barrier + 1);
        }

        // 2. hT0 (32 even swaps/chunk -> result in hT0) -> h_last
        transpose_kernel<<<dim3(32, 8), blk, 0, stream>>>(hT0, hlast);

        // 3. hid = relu(h_T @ W1 + b1); logits = hid @ W2 + b2
        gemm_kernel<<<grdH, blk, 0, stream>>>(
            hlast, 0, 0, H_, H_, nullptr, 0, 0, W1, nullptr, b1, flag,
            hid, B_, H_, 1);
        gemm_kernel<<<grdA, blk, 0, stream>>>(
            hid, 0, 0, H_, H_, nullptr, 0, 0, W2, nullptr, b2, flag,
            logits, B_, A_, 0);

        // 4. softmax -> gumbel argmax -> loss
        sample_kernel<<<dim3(B_), blk, 0, stream>>>(logits, out, loss_acc);
        finalize_kernel<<<1, 1, 0, stream>>>(loss_acc, out);
        return;
    }

    // ---------------- FALLBACK: verbatim verified path ----------------
    float* hA       = ws;                       // [B,H]
    float* hB       = hA + (long)B_ * H_;       // [B,H]
    float* hid      = hB + (long)B_ * H_;       // [B,H]
    float* logits   = hid + (long)B_ * H_;      // [B,A]
    float* loss_acc = logits + (long)B_ * A_;   // [1]
    int*   flag     = (int*)(loss_acc + 1);     // [1] dtype flag

    hipMemsetAsync(hA, 0, (size_t)B_ * H_ * sizeof(float), stream);
    hipMemsetAsync(loss_acc, 0, sizeof(float), stream);

    detect_kernel<<<1, blk, 0, stream>>>((const unsigned*)Wx, flag);

    float* hp = hA;
    float* hn = hB;
    for (int t = 0; t < T_; ++t) {
        gemm_kernel<<<grdH, blk, 0, stream>>>(
            inputs, 1, (long)t * F_, T_ * F_, F_,
            hp, H_, H_,
            Wx, Wh, b_rnn, flag,
            hn, B_, H_, 1);
        float* tmp = hp; hp = hn; hn = tmp;
    }

    gemm_kernel<<<grdH, blk, 0, stream>>>(
        hp, 0, 0, H_, H_, nullptr, 0, 0, W1, nullptr, b1, flag, hid, B_, H_, 1);
    gemm_kernel<<<grdA, blk, 0, stream>>>(
        hid, 0, 0, H_, H_, nullptr, 0, 0, W2, nullptr, b2, flag, logits, B_, A_, 0);

    sample_kernel<<<dim3(B_), blk, 0, stream>>>(logits, out, loss_acc);
    finalize_kernel<<<1, 1, 0, stream>>>(loss_acc, out);
}

// Round 17
// 4932.118 us; speedup vs baseline: 2.6519x; 2.6519x over previous
//
#include <hip/hip_runtime.h>
#include <hip/hip_bf16.h>

#define B_ 256
#define T_ 256
#define F_ 512
#define H_ 1024
#define A_ 1000
#define EPS_ 1e-7f

typedef __hip_bfloat16 bf16;

// ---------------------------------------------------------------------------
// State of knowledge (round 26 == v5 resubmit x6; r20 "container failed
// twice", r21-r25 GPUAcquisitionTimeout — rnn_step5 has NEVER run on HW.
// All failures at acquisition, pre-compile. Bundling xw_gemm re-evaluated
// and rejected again: v5-only pass banks ~1ms at low risk; a blind xw
// rewrite (~20-30% bug risk) would convert that to a wasted slot):
//  - CORRECTNESS LOCKED (harness-verified r9 @31109, r10 @14771, r12 @5401,
//    r15 @7078, r17 @5611, r19 @13079us, all absmax 0.0): d_out FLOAT32
//    [action(256), loss(1)]; RNG = V4 partitionable xor-fold threefry
//    (o0^o1), key(42)->(0,42); gumbel-argmax first-index tie-break; dtype
//    runtime-detect from Wx. detect/sample/finalize/gemm/xw_gemm/threefry
//    byte-identical to verified. DO NOT TOUCH.
//  - r19 COUNTERS: persistent grid-barrier scan FAILED: 45us/step,
//    VALUBusy 8.6%, FETCH 4.8MB/step — per-step device-scope fencing
//    invalidates L2. PERSISTENT + CROSS-XCD BARRIER PER STEP = DEAD END.
//  - MODEL: launch overhead SMALL (~1-2us). v2 (14.5us/step) VMEM-ISSUE
//    bound (8192 VMEM inst/CU/step); v4 (15.3) LDS-READ-ISSUE bound
//    (4096 b128 + 1024 VMEM). Lever = memory-instruction count per FMA.
//  - v5 (this kernel): block 8n x 128m (grid 128x2), lane loads float2 of
//    h (1 VMEM/k), whp[1024][8] panel (32KB, 2 b128 broadcasts/k), 16
//    FMA/k/lane, part[16][8][128] (64KB). Per CU/step: 1024 VMEM + 2048
//    LDS-read inst. Per-output sum order BIT-IDENTICAL to verified v4
//    (16x64 k-split, asc k, asc q, +xw last).
//  - Predict: step 9-11us, scan ~2.7ms, total ~4.3-4.6ms. Decision:
//    (a) ok -> BK=32 dbuf xw_gemm next (1.35ms @ ~50TF -> ~0.9ms);
//    (b) step >=13us -> revert scan to v2, remaining rounds on xw_gemm;
//    (c) absmax!=0 -> revert v2; (d) infra -> resubmit.
// ---------------------------------------------------------------------------
__global__ __launch_bounds__(256) void detect_kernel(
    const unsigned* __restrict__ wx_words, int* __restrict__ flag)
{
    __shared__ int cnt[256];
    const int tid = threadIdx.x;
    int c = 0;
    for (int k = tid; k < 65536; k += 256) {
        unsigned lo = wx_words[k] & 0xFFFFu;
        unsigned e = (lo >> 7) & 0xFFu;
        if (e >= 105u && e <= 126u) c++;   // |v| in [2^-22, 0.5]: bf16 weight-like
    }
    cnt[tid] = c;
    __syncthreads();
    for (int s = 128; s > 0; s >>= 1) {
        if (tid < s) cnt[tid] += cnt[tid + s];
        __syncthreads();
    }
    if (tid == 0) flag[0] = (cnt[0] > 32768) ? 1 : 0;   // 1 => bf16-packed
}

__device__ __forceinline__ float load_maybe(const void* p, long i, int isbf16)
{
    return isbf16 ? __bfloat162float(((const bf16*)p)[i])
                  : ((const float*)p)[i];
}

// ---------------------------------------------------------------------------
// OLD fused GEMM (verified): kept for fallback path and layers 2/3.
// ---------------------------------------------------------------------------
__global__ __launch_bounds__(256) void gemm_kernel(
    const void* __restrict__ A1, int a1_maybe, long a1_off, int lda1, int K1,
    const float* __restrict__ A2, int lda2, int K2,
    const void* __restrict__ Wa, const void* __restrict__ Wb,
    const void* __restrict__ bias,
    const int* __restrict__ flagp,
    float* __restrict__ C, int M, int N, int do_relu)
{
    const int flagv = flagp[0];          // uniform; L2-hit
    const int a1_bf = a1_maybe ? flagv : 0;

    __shared__ float As[32][33];
    __shared__ float Bs[32][33];

    const int tid = threadIdx.x;
    const int tx = tid & 15;
    const int ty = tid >> 4;
    const int n0 = blockIdx.x * 32;
    const int m0 = blockIdx.y * 32;

    float acc00 = 0.f, acc01 = 0.f, acc10 = 0.f, acc11 = 0.f;

    for (int part = 0; part < 2; ++part) {
        const void* Wp = part ? Wb : Wa;
        const int    K = part ? K2 : K1;
        if (part == 1 && (A2 == nullptr || K2 <= 0)) continue;

        for (int k0 = 0; k0 < K; k0 += 32) {
            #pragma unroll
            for (int i = 0; i < 4; ++i) {
                int idx = tid + i * 256;
                int r = idx >> 5, c = idx & 31;
                float av;
                if (part == 0) {
                    long off = a1_off + (long)(m0 + r) * lda1 + (k0 + c);
                    av = load_maybe(A1, off, a1_bf);
                } else {
                    av = A2[(long)(m0 + r) * lda2 + (k0 + c)];
                }
                As[r][c] = av;
                int n = n0 + c;
                Bs[r][c] = (n < N) ? load_maybe(Wp, (long)(k0 + r) * N + n, flagv)
                                   : 0.0f;
            }
            __syncthreads();
            #pragma unroll
            for (int k = 0; k < 32; ++k) {
                float a0 = As[ty * 2][k];
                float a1 = As[ty * 2 + 1][k];
                float b0 = Bs[k][tx * 2];
                float b1 = Bs[k][tx * 2 + 1];
                acc00 = fmaf(a0, b0, acc00); acc01 = fmaf(a0, b1, acc01);
                acc10 = fmaf(a1, b0, acc10); acc11 = fmaf(a1, b1, acc11);
            }
            __syncthreads();
        }
    }

    const int m = m0 + ty * 2;
    const int n = n0 + tx * 2;
    float bs0 = (n     < N) ? load_maybe(bias, n,     flagv) : 0.0f;
    float bs1 = (n + 1 < N) ? load_maybe(bias, n + 1, flagv) : 0.0f;
    float v00 = acc00 + bs0, v01 = acc01 + bs1;
    float v10 = acc10 + bs0, v11 = acc11 + bs1;
    if (do_relu) {
        v00 = fmaxf(v00, 0.f); v01 = fmaxf(v01, 0.f);
        v10 = fmaxf(v10, 0.f); v11 = fmaxf(v11, 0.f);
    }
    if (n     < N) C[(long)m * N + n]           = v00;
    if (n + 1 < N) C[(long)m * N + n + 1]       = v01;
    if (n     < N) C[(long)(m + 1) * N + n]     = v10;
    if (n + 1 < N) C[(long)(m + 1) * N + n + 1] = v11;
}

// ---------------------------------------------------------------------------
// XW chunk GEMM (verified r10). C[8192][1024] = inputs_chunk @ Wx + b_rnn.
// Chunk rows r = b*32 + tl  <->  input row b*256 + (t0 + tl).
// 128x128 tile, BK=16, 8x8 micro, 256 threads. Grid (8, 64).
// ---------------------------------------------------------------------------
__global__ __launch_bounds__(256, 2) void xw_gemm_kernel(
    const void* __restrict__ X,      // inputs, dual dtype
    const void* __restrict__ Wx,     // [512][1024], dual dtype
    const void* __restrict__ brnn,   // [1024], dual dtype
    const int* __restrict__ flagp,
    float* __restrict__ C,           // [8192][1024] chunk buffer
    int t0)
{
    const int flagv = flagp[0];
    __shared__ float As[16][132];    // k-major: As[k][m]
    __shared__ float Bs[16][132];    // Bs[k][n]

    const int tid = threadIdx.x;
    const int tx = tid & 15;
    const int ty = tid >> 4;
    const int n0 = blockIdx.x * 128;
    const int m0 = blockIdx.y * 128;

    float acc[8][8] = {{0.f}};

    for (int k0 = 0; k0 < F_; k0 += 16) {
        #pragma unroll
        for (int i = 0; i < 8; ++i) {
            int idx = tid + i * 256;            // 0..2047
            // A: 128 rows x 16 k, consecutive tid -> consecutive k
            int ka = idx & 15, r = idx >> 4;
            int rg = m0 + r;
            long irow = (long)(rg >> 5) * 256 + t0 + (rg & 31);
            As[ka][r] = load_maybe(X, irow * F_ + k0 + ka, flagv);
            // B: 16 k x 128 n, consecutive tid -> consecutive n
            int nb = idx & 127, kb = idx >> 7;
            Bs[kb][nb] = load_maybe(Wx, (long)(k0 + kb) * H_ + n0 + nb, flagv);
        }
        __syncthreads();
        #pragma unroll
        for (int k = 0; k < 16; ++k) {
            float4 a0 = *(const float4*)&As[k][ty * 4];
            float4 a1 = *(const float4*)&As[k][ty * 4 + 64];
            float4 b0 = *(const float4*)&Bs[k][tx * 4];
            float4 b1 = *(const float4*)&Bs[k][tx * 4 + 64];
            float av[8] = {a0.x, a0.y, a0.z, a0.w, a1.x, a1.y, a1.z, a1.w};
            float bv[8] = {b0.x, b0.y, b0.z, b0.w, b1.x, b1.y, b1.z, b1.w};
            #pragma unroll
            for (int i = 0; i < 8; ++i)
                #pragma unroll
                for (int j = 0; j < 8; ++j)
                    acc[i][j] = fmaf(av[i], bv[j], acc[i][j]);
        }
        __syncthreads();
    }

    float bb[8];
    #pragma unroll
    for (int j = 0; j < 8; ++j) {
        int n = n0 + tx * 4 + (j & 3) + (j >> 2) * 64;
        bb[j] = load_maybe(brnn, n, flagv);
    }
    #pragma unroll
    for (int i = 0; i < 8; ++i) {
        int m = m0 + ty * 4 + (i & 3) + (i >> 2) * 64;
        float4 v0 = {acc[i][0] + bb[0], acc[i][1] + bb[1],
                     acc[i][2] + bb[2], acc[i][3] + bb[3]};
        float4 v1 = {acc[i][4] + bb[4], acc[i][5] + bb[5],
                     acc[i][6] + bb[6], acc[i][7] + bb[7]};
        *(float4*)&C[(long)m * H_ + n0 + tx * 4]      = v0;
        *(float4*)&C[(long)m * H_ + n0 + tx * 4 + 64] = v1;
    }
}

// ---------------------------------------------------------------------------
// Wh -> fp32 copy (handles bf16-packed mode once, outside the scan).
// ---------------------------------------------------------------------------
__global__ __launch_bounds__(256) void convert_wh_kernel(
    const void* __restrict__ Wh, const int* __restrict__ flagp,
    float* __restrict__ whf)
{
    const int flagv = flagp[0];
    long i = (long)blockIdx.x * 256 + threadIdx.x;
    whf[i] = load_maybe(Wh, i, flagv);
}

// ---------------------------------------------------------------------------
// v5: RNN scan step — halve memory-instruction count per FMA.
//   hTn[n][m] = relu( xw[m][tl][n] + sum_k hT[k][m] * Wh[k][n] )
// Grid (128 nb, 2 mb) x 1024 threads (16 waves). Block owns 8 n x 128 m.
//   wave q = k-segment (64 k each); lane covers m = m0 + 2*lane (float2).
// LDS: whp[1024][8] panel (32KB, loaded once/step);
//      part[16][8][128] partials (64KB). Total 96KB -> 1 block/CU.
// Per k per wave: 1 float2 coalesced global h (512B) + 2 ds_read_b128
// broadcasts + 16 FMA. Per CU per step: 1024 VMEM + 2048 LDS-read inst
// (vs v2's 8192 VMEM / v4's 1024+4096) -> issue-bound at ~7us model.
// Per-output sum order BIT-IDENTICAL to verified v4: ascending k within
// 64-k wave segment, combine ascending q, + xw last, relu.
// ---------------------------------------------------------------------------
__global__ __launch_bounds__(1024) void rnn_step5_kernel(
    const float* __restrict__ hT,     // [1024][256]
    const float* __restrict__ Wh,     // [1024][1024] fp32
    const float* __restrict__ xw,     // xwbuf + tl*1024
    float* __restrict__ hTn)          // [1024][256]
{
    __shared__ float whp[1024][8];       // 32 KB Wh panel
    __shared__ float part[16][8][128];   // 64 KB partials [q][n][m]

    const int tid  = threadIdx.x;
    const int lane = tid & 63;
    const int q    = __builtin_amdgcn_readfirstlane(tid >> 6);  // k-segment
    const int n0   = blockIdx.x * 8;
    const int m0   = blockIdx.y * 128;

    // --- panel load: thread t -> Wh row t, cols n0..n0+7 (2 float4) ---
    {
        const float4* src = (const float4*)(Wh + (long)tid * H_ + n0);
        float4 p0 = src[0], p1 = src[1];
        *(float4*)&whp[tid][0] = p0;
        *(float4*)&whp[tid][4] = p1;
    }
    __syncthreads();

    // --- main: 64 k per wave; per k: 1 float2 h + 2 b128 panel + 16 FMA ---
    const float* __restrict__ hp = hT + (((long)q << 6) << 8) + m0 + lane * 2;
    float acc0[8], acc1[8];
    #pragma unroll
    for (int i = 0; i < 8; ++i) { acc0[i] = 0.f; acc1[i] = 0.f; }

    #pragma unroll 4
    for (int k = 0; k < 64; ++k) {
        float2 hv = *(const float2*)(hp + (k << 8));
        const int kk = (q << 6) + k;
        float4 w0 = *(const float4*)&whp[kk][0];
        float4 w1 = *(const float4*)&whp[kk][4];
        acc0[0] = fmaf(hv.x, w0.x, acc0[0]);
        acc0[1] = fmaf(hv.x, w0.y, acc0[1]);
        acc0[2] = fmaf(hv.x, w0.z, acc0[2]);
        acc0[3] = fmaf(hv.x, w0.w, acc0[3]);
        acc0[4] = fmaf(hv.x, w1.x, acc0[4]);
        acc0[5] = fmaf(hv.x, w1.y, acc0[5]);
        acc0[6] = fmaf(hv.x, w1.z, acc0[6]);
        acc0[7] = fmaf(hv.x, w1.w, acc0[7]);
        acc1[0] = fmaf(hv.y, w0.x, acc1[0]);
        acc1[1] = fmaf(hv.y, w0.y, acc1[1]);
        acc1[2] = fmaf(hv.y, w0.z, acc1[2]);
        acc1[3] = fmaf(hv.y, w0.w, acc1[3]);
        acc1[4] = fmaf(hv.y, w1.x, acc1[4]);
        acc1[5] = fmaf(hv.y, w1.y, acc1[5]);
        acc1[6] = fmaf(hv.y, w1.z, acc1[6]);
        acc1[7] = fmaf(hv.y, w1.w, acc1[7]);
    }

    // --- partials: float2 store, lane-stride-1 (2-way banks = free) ---
    #pragma unroll
    for (int n = 0; n < 8; ++n) {
        *(float2*)&part[q][n][lane * 2] = make_float2(acc0[n], acc1[n]);
    }
    __syncthreads();

    // --- combine: thread (mi = tid&127, ni = tid>>7); ascending q ---
    const int mi = tid & 127;
    const int ni = tid >> 7;
    float s = part[0][ni][mi];
    #pragma unroll
    for (int qq = 1; qq < 16; ++qq) s += part[qq][ni][mi];

    const int gm = m0 + mi;
    const int gn = n0 + ni;
    const float xv = xw[(long)gm * (32 * 1024) + gn];
    hTn[(long)gn * 256 + gm] = fmaxf(s + xv, 0.f);   // coalesced store
}

// ---------------------------------------------------------------------------
// transpose hT[1024][256] -> h_last[256][1024] for layer 2.
// ---------------------------------------------------------------------------
__global__ __launch_bounds__(256) void transpose_kernel(
    const float* __restrict__ in,   // [1024][256]
    float* __restrict__ out)        // [256][1024]
{
    __shared__ float t[32][33];
    const int tid = threadIdx.x;
    const int c  = tid & 31;
    const int r8 = tid >> 5;
    const int x0 = blockIdx.x * 32;   // over 1024
    const int y0 = blockIdx.y * 32;   // over 256
    #pragma unroll
    for (int i = 0; i < 4; ++i) {
        int r = r8 + i * 8;
        t[r][c] = in[(long)(x0 + r) * 256 + y0 + c];
    }
    __syncthreads();
    #pragma unroll
    for (int i = 0; i < 4; ++i) {
        int r = r8 + i * 8;
        out[(long)(y0 + r) * 1024 + x0 + c] = t[c][r];
    }
}

// ---------------------------------------------------------------------------
// Threefry2x32, 20 rounds — matches JAX exactly. key(42) => (k0,k1)=(0,42).
// ---------------------------------------------------------------------------
__device__ __forceinline__ unsigned rotl32(unsigned v, int r) {
    return (v << r) | (v >> (32 - r));
}

__device__ __forceinline__ void threefry2x32(unsigned k0, unsigned k1,
                                             unsigned x0, unsigned x1,
                                             unsigned& o0, unsigned& o1)
{
    unsigned ks2 = k0 ^ k1 ^ 0x1BD11BDAu;
    x0 += k0; x1 += k1;
#define R4(ra, rb, rc, rd)                              \
    x0 += x1; x1 = rotl32(x1, ra); x1 ^= x0;            \
    x0 += x1; x1 = rotl32(x1, rb); x1 ^= x0;            \
    x0 += x1; x1 = rotl32(x1, rc); x1 ^= x0;            \
    x0 += x1; x1 = rotl32(x1, rd); x1 ^= x0;
    R4(13, 15, 26, 6);  x0 += k1;  x1 += ks2 + 1u;
    R4(17, 29, 16, 24); x0 += ks2; x1 += k0  + 2u;
    R4(13, 15, 26, 6);  x0 += k0;  x1 += k1  + 3u;
    R4(17, 29, 16, 24); x0 += k1;  x1 += ks2 + 4u;
    R4(13, 15, 26, 6);  x0 += ks2; x1 += k0  + 5u;
#undef R4
    o0 = x0; o1 = x1;
}

// Gumbel at flat index j of the (256,1000) draw, key(42).
// V4 partitionable xor-fold (VERIFIED): counts (hi=0, lo=j), bits = o0^o1.
__device__ __forceinline__ float gumbel_at(unsigned j)
{
    unsigned o0, o1;
    threefry2x32(0u, 42u, 0u, j, o0, o1);
    unsigned bits = o0 ^ o1;                       // V4: xor-fold
    unsigned ub = (bits >> 9) | 0x3F800000u;       // [1,2)
    float u = __uint_as_float(ub) - 1.0f;          // [0,1)
    const float TINY = 1.1754943508222875e-38f;    // finfo(f32).tiny
    u = fmaxf(TINY, u * (1.0f - TINY) + TINY);     // JAX uniform(minval=tiny)
    return -logf(-logf(u));
}

// ---------------------------------------------------------------------------
// Softmax + gumbel-argmax sampling + loss. One block per batch row.
// OUTPUT IS FLOAT32. besti canary = 500.
// ---------------------------------------------------------------------------
__global__ __launch_bounds__(256) void sample_kernel(
    const float* __restrict__ logits,      // [B_, A_]
    float* __restrict__ out,               // out[b] = action as float32
    float* __restrict__ loss_acc)          // pre-zeroed scalar
{
    const int b = blockIdx.x;
    const int tid = threadIdx.x;
    const float* row = logits + (long)b * A_;

    __shared__ float sv[256];
    __shared__ int   si[256];

    // 1. row max
    float lv[4];
    float lmax = -INFINITY;
    #pragma unroll
    for (int i = 0; i < 4; ++i) {
        int a = tid + i * 256;
        lv[i] = (a < A_) ? row[a] : -INFINITY;
        lmax = fmaxf(lmax, lv[i]);
    }
    sv[tid] = lmax;
    __syncthreads();
    for (int s = 128; s > 0; s >>= 1) {
        if (tid < s) sv[tid] = fmaxf(sv[tid], sv[tid + s]);
        __syncthreads();
    }
    lmax = sv[0];
    __syncthreads();

    // 2. exp + sum
    float e[4];
    float lsum = 0.f;
    #pragma unroll
    for (int i = 0; i < 4; ++i) {
        int a = tid + i * 256;
        e[i] = (a < A_) ? expf(lv[i] - lmax) : 0.0f;
        lsum += e[i];
    }
    sv[tid] = lsum;
    __syncthreads();
    for (int s = 128; s > 0; s >>= 1) {
        if (tid < s) sv[tid] += sv[tid + s];
        __syncthreads();
    }
    const float inv = 1.0f / sv[0];
    __syncthreads();

    // 3. score = prob + gumbel; argmax, first-index tie-break (np.argmax)
    float bestv = -INFINITY;
    int   besti = 500;                     // NaN canary
    #pragma unroll
    for (int i = 0; i < 4; ++i) {
        int a = tid + i * 256;
        if (a < A_) {
            float score = e[i] * inv + gumbel_at((unsigned)(b * A_ + a));
            if (score > bestv) { bestv = score; besti = a; }
        }
    }
    sv[tid] = bestv; si[tid] = besti;
    __syncthreads();
    for (int s = 128; s > 0; s >>= 1) {
        if (tid < s) {
            float v2 = sv[tid + s]; int i2 = si[tid + s];
            if (v2 > sv[tid] || (v2 == sv[tid] && i2 < si[tid])) {
                sv[tid] = v2; si[tid] = i2;
            }
        }
        __syncthreads();
    }

    if (tid == 0) {
        int act = si[0];
        out[b] = (float)act;                       // float32 action
        float p = expf(row[act] - lmax) * inv;
        p = fminf(fmaxf(p, EPS_), 1.0f - EPS_);
        atomicAdd(loss_acc, -logf(p) * (1.0f / (float)B_));
    }
}

__global__ void finalize_kernel(const float* __restrict__ loss_acc,
                                float* __restrict__ out)
{
    out[B_] = *loss_acc;                           // float32 loss
}

// ---------------------------------------------------------------------------
extern "C" void kernel_launch(void* const* d_in, const int* in_sizes, int n_in,
                              void* d_out, int out_size, void* d_ws, size_t ws_size,
                              hipStream_t stream)
{
    (void)out_size;

    // Size-based pointer mapping (removes any ordering assumption).
    const void *inputs = nullptr, *Wx = nullptr, *Wh = nullptr, *b_rnn = nullptr,
               *W1 = nullptr, *b1 = nullptr, *W2 = nullptr, *b2 = nullptr;
    for (int i = 0; i < n_in; ++i) {
        int s = in_sizes[i];
        if      (s == 33554432) inputs = d_in[i];
        else if (s == 524288)   Wx = d_in[i];
        else if (s == 1048576)  { if (!Wh) Wh = d_in[i]; else W1 = d_in[i]; }
        else if (s == 1024)     { if (!b_rnn) b_rnn = d_in[i]; else b1 = d_in[i]; }
        else if (s == 1024000)  W2 = d_in[i];
        else if (s == 1000)     b2 = d_in[i];
    }
    if (!inputs) inputs = d_in[0];
    if (!Wx) Wx = d_in[1];  if (!Wh) Wh = d_in[2];  if (!b_rnn) b_rnn = d_in[3];
    if (!W1) W1 = d_in[4];  if (!b1) b1 = d_in[5];  if (!W2) W2 = d_in[6];
    if (!b2) b2 = d_in[7];

    float* out = (float*)d_out;            // FLOAT32 output buffer
    float* ws = (float*)d_ws;

    dim3 blk(256);
    dim3 grdH((H_ + 31) / 32, B_ / 32);   // 32 x 8
    dim3 grdA((A_ + 31) / 32, B_ / 32);

    // Workspace demand for the fast path (~43 MB in floats):
    const size_t XW_FLOATS = (size_t)8192 * 1024;     // 8,388,608 (32-t chunk)
    const size_t need_floats = XW_FLOATS + 2 * 262144 + 1048576
                             + 262144 + 262144 + 256000 + 8;
    if (ws_size >= need_floats * sizeof(float)) {
        // ---------------- FAST PATH (round 26) ----------------
        float* xwbuf    = ws;                          // [8192][1024]
        float* hT0      = xwbuf + XW_FLOATS;           // [1024][256]
        float* hT1      = hT0 + 262144;                // [1024][256]
        float* whf      = hT1 + 262144;                // [1024][1024]
        float* hlast    = whf + 1048576;               // [256][1024]
        float* hid      = hlast + 262144;              // [256][1024]
        float* logits   = hid + 262144;                // [256][1000]
        float* loss_acc = logits + 256000;             // [1]
        int*   flag     = (int*)(loss_acc + 1);        // [1]

        hipMemsetAsync(hT0, 0, 262144 * sizeof(float), stream);
        hipMemsetAsync(loss_acc, 0, sizeof(float), stream);

        // 0. dtype detect, Wh -> fp32
        detect_kernel<<<1, blk, 0, stream>>>((const unsigned*)Wx, flag);
        convert_wh_kernel<<<4096, blk, 0, stream>>>(Wh, flag, whf);

        // 1. scan: per 32-t chunk, precompute XW then run 32 steps
        float* hp = hT0;
        float* hn = hT1;
        for (int c = 0; c < 8; ++c) {
            xw_gemm_kernel<<<dim3(8, 64), blk, 0, stream>>>(
                inputs, Wx, b_rnn, flag, xwbuf, c * 32);
            for (int tl = 0; tl < 32; ++tl) {
                rnn_step5_kernel<<<dim3(128, 2), dim3(1024), 0, stream>>>(
                    hp, whf, xwbuf + (long)tl * 1024, hn);
                float* tmp = hp; hp = hn; hn = tmp;
            }
        }

        // 2. hT -> h_last (natural layout) for the dense layers
        transpose_kernel<<<dim3(32, 8), blk, 0, stream>>>(hp, hlast);

        // 3. hid = relu(h_T @ W1 + b1); logits = hid @ W2 + b2
        gemm_kernel<<<grdH, blk, 0, stream>>>(
            hlast, 0, 0, H_, H_, nullptr, 0, 0, W1, nullptr, b1, flag,
            hid, B_, H_, 1);
        gemm_kernel<<<grdA, blk, 0, stream>>>(
            hid, 0, 0, H_, H_, nullptr, 0, 0, W2, nullptr, b2, flag,
            logits, B_, A_, 0);

        // 4. softmax -> gumbel argmax -> loss
        sample_kernel<<<dim3(B_), blk, 0, stream>>>(logits, out, loss_acc);
        finalize_kernel<<<1, 1, 0, stream>>>(loss_acc, out);
        return;
    }

    // ---------------- FALLBACK: verbatim verified path ----------------
    float* hA       = ws;                       // [B,H]
    float* hB       = hA + (long)B_ * H_;       // [B,H]
    float* hid      = hB + (long)B_ * H_;       // [B,H]
    float* logits   = hid + (long)B_ * H_;      // [B,A]
    float* loss_acc = logits + (long)B_ * A_;   // [1]
    int*   flag     = (int*)(loss_acc + 1);     // [1] dtype flag

    hipMemsetAsync(hA, 0, (size_t)B_ * H_ * sizeof(float), stream);
    hipMemsetAsync(loss_acc, 0, sizeof(float), stream);

    detect_kernel<<<1, blk, 0, stream>>>((const unsigned*)Wx, flag);

    float* hp = hA;
    float* hn = hB;
    for (int t = 0; t < T_; ++t) {
        gemm_kernel<<<grdH, blk, 0, stream>>>(
            inputs, 1, (long)t * F_, T_ * F_, F_,
            hp, H_, H_,
            Wx, Wh, b_rnn, flag,
            hn, B_, H_, 1);
        float* tmp = hp; hp = hn; hn = tmp;
    }

    gemm_kernel<<<grdH, blk, 0, stream>>>(
        hp, 0, 0, H_, H_, nullptr, 0, 0, W1, nullptr, b1, flag, hid, B_, H_, 1);
    gemm_kernel<<<grdA, blk, 0, stream>>>(
        hid, 0, 0, H_, H_, nullptr, 0, 0, W2, nullptr, b2, flag, logits, B_, A_, 0);

    sample_kernel<<<dim3(B_), blk, 0, stream>>>(logits, out, loss_acc);
    finalize_kernel<<<1, 1, 0, stream>>>(loss_acc, out);
}